// Round 4
// baseline (1211.912 us; speedup 1.0000x reference)
//
#include <hip/hip_runtime.h>
#include <cmath>

#define L_LEVELS 16
#define T_SIZE 524288u
#define T_MASK (T_SIZE - 1u)
#define P1 2654435761u
#define P2 805459861u

struct ResArr { int r[L_LEVELS]; };

// ---------------------------------------------------------------------------
// Per-point encode for one level. Corner-pair x-compression (round-3 win):
// corners j and j+4 differ only in x: h_{j+4} = h_j ^ diffx, diffx=hx0^(hx0+1).
// If ix even: diffx==1 and the pair {h,h^1} is ONE aligned float4 (16B load
// serves both corners). Else 4 extra exec-masked float2 loads (masked lanes
// issue no L2 requests). 8 -> ~6 gather requests per point-level.
// ---------------------------------------------------------------------------
__device__ __forceinline__ float2 encode_point(
    float px, float py, float pz, float rf,
    const float2* __restrict__ E, const float4* __restrict__ E4)
{
    // single fp32 multiplies to bit-match reference rounding
    const float sx = px * rf, sy = py * rf, sz = pz * rf;
    const int ix = (int)sx, iy = (int)sy, iz = (int)sz;  // x>=0 -> trunc==floor
    const float fx = sx - (float)ix;
    const float fy = sy - (float)iy;
    const float fz = sz - (float)iz;

    // hash keeps only low 19 bits -> uint32 arithmetic exact vs int64 reference
    const unsigned hx0 = (unsigned)ix,      hx1 = hx0 + 1u;
    const unsigned hy0 = (unsigned)iy * P1, hy1 = hy0 + P1;
    const unsigned hz0 = (unsigned)iz * P2, hz1 = hz0 + P2;
    const unsigned diffx = hx0 ^ hx1;      // 2^k-1 pattern, < 2^19 (ix<=2048)

    const unsigned h0 = (hx0 ^ hy0 ^ hz0) & T_MASK;
    const unsigned h1 = (hx0 ^ hy0 ^ hz1) & T_MASK;
    const unsigned h2 = (hx0 ^ hy1 ^ hz0) & T_MASK;
    const unsigned h3 = (hx0 ^ hy1 ^ hz1) & T_MASK;

    // One aligned float4 per pair: slots {h&~1, h|1}.
    const float4 v0 = E4[h0 >> 1];
    const float4 v1 = E4[h1 >> 1];
    const float4 v2 = E4[h2 >> 1];
    const float4 v3 = E4[h3 >> 1];

    const bool odd0 = (h0 & 1u), odd1 = (h1 & 1u), odd2 = (h2 & 1u), odd3 = (h3 & 1u);
    const float2 c0v = odd0 ? make_float2(v0.z, v0.w) : make_float2(v0.x, v0.y);
    const float2 c1v = odd1 ? make_float2(v1.z, v1.w) : make_float2(v1.x, v1.y);
    const float2 c2v = odd2 ? make_float2(v2.z, v2.w) : make_float2(v2.x, v2.y);
    const float2 c3v = odd3 ? make_float2(v3.z, v3.w) : make_float2(v3.x, v3.y);

    // partner corner (x+1): valid from v* iff diffx==1 (then h^1 = other half)
    float2 c4v = odd0 ? make_float2(v0.x, v0.y) : make_float2(v0.z, v0.w);
    float2 c5v = odd1 ? make_float2(v1.x, v1.y) : make_float2(v1.z, v1.w);
    float2 c6v = odd2 ? make_float2(v2.x, v2.y) : make_float2(v2.z, v2.w);
    float2 c7v = odd3 ? make_float2(v3.x, v3.y) : make_float2(v3.z, v3.w);
    if (diffx != 1u) {          // ~half the lanes; masked lanes issue no requests
        c4v = E[h0 ^ diffx];
        c5v = E[h1 ^ diffx];
        c6v = E[h2 ^ diffx];
        c7v = E[h3 ^ diffx];
    }

    const float gx = 1.0f - fx, gy = 1.0f - fy, gz = 1.0f - fz;
    // exact reference association: a*(1-f) + b*f
    const float c00x = c0v.x * gx + c4v.x * fx;
    const float c00y = c0v.y * gx + c4v.y * fx;
    const float c01x = c1v.x * gx + c5v.x * fx;
    const float c01y = c1v.y * gx + c5v.y * fx;
    const float c10x = c2v.x * gx + c6v.x * fx;
    const float c10y = c2v.y * gx + c6v.y * fx;
    const float c11x = c3v.x * gx + c7v.x * fx;
    const float c11y = c3v.y * gx + c7v.y * fx;

    const float a0x = c00x * gy + c10x * fy;
    const float a0y = c00y * gy + c10y * fy;
    const float a1x = c01x * gy + c11x * fy;
    const float a1y = c01y * gy + c11y * fy;

    return make_float2(a0x * gz + a1x * fz, a0y * gz + a1y * fz);
}

// ---------------------------------------------------------------------------
// K1: TWO points per thread (round-4 change). grid = (npts/512, 16 levels),
// x-fastest dispatch => levels processed ~sequentially => each XCD's 4MB L2
// holds the current level's 4MB table (~95% hit, FETCH~830MB).
// Rationale: round-3 cut requests 278M->211M but time only -8%; if a per-wave
// issue/latency component is the secondary limiter, doubling per-thread MLP
// (16 independent gathers in flight) recovers it. If flat, we are at the L2
// request-rate floor (6 gathers/point-level is irreducible for this hash).
// Thread t handles p0=pbase+t and p1=pbase+256+t: both ws stores stay
// full-line 512B/wave coalesced; LDS read pattern stays conflict-free.
// (Round-1 lesson: never partial-line scatter the output -> RFO + 4x write
// amplification. ws stays level-major.)
// ---------------------------------------------------------------------------
__global__ __launch_bounds__(256) void enc_level_kernel(
    const float* __restrict__ x,
    const float* __restrict__ emb,
    float2* __restrict__ ws,
    ResArr res, int npts)
{
    __shared__ float xsh[1536];          // 512 points * 3 coords
    const int tid   = threadIdx.x;
    const int level = blockIdx.y;
    const int pbase = blockIdx.x * 512;

    // stage x: 384 float4 loads cover 1536 floats, fully coalesced
    if (pbase + 512 <= npts) {
        ((float4*)xsh)[tid] = ((const float4*)(x + (size_t)pbase * 3))[tid];
        if (tid < 128)
            ((float4*)xsh)[256 + tid] =
                ((const float4*)(x + (size_t)pbase * 3))[256 + tid];
    } else {
        const int nfl = npts * 3 - pbase * 3;
        for (int i = tid; i < nfl; i += 256) xsh[i] = x[(size_t)pbase * 3 + i];
    }
    __syncthreads();

    const float rf = (float)res.r[level];
    const float2* __restrict__ E  = (const float2*)emb + (size_t)level * T_SIZE;
    const float4* __restrict__ E4 = (const float4*)E;

    const int p0 = pbase + tid;
    const int p1 = pbase + 256 + tid;

    // lds[3t+c]: 3t mod 32 covers all banks, 2 lanes/bank -> conflict-free
    if (p1 < npts) {
        const float2 r0 = encode_point(xsh[tid * 3 + 0], xsh[tid * 3 + 1],
                                       xsh[tid * 3 + 2], rf, E, E4);
        const float2 r1 = encode_point(xsh[768 + tid * 3 + 0], xsh[768 + tid * 3 + 1],
                                       xsh[768 + tid * 3 + 2], rf, E, E4);
        ws[(size_t)level * npts + p0] = r0;
        ws[(size_t)level * npts + p1] = r1;
    } else if (p0 < npts) {
        const float2 r0 = encode_point(xsh[tid * 3 + 0], xsh[tid * 3 + 1],
                                       xsh[tid * 3 + 2], rf, E, E4);
        ws[(size_t)level * npts + p0] = r0;
    }
}

// ---------------------------------------------------------------------------
// K2: LDS-tiled transpose ws[level][point] -> out[point][level]. ~107us
// (512MB at ~4.8 TB/s effective). Near roofline; unchanged.
// ---------------------------------------------------------------------------
__global__ __launch_bounds__(256) void transpose_tile_kernel(
    const float2* __restrict__ ws, float4* __restrict__ out4, int npts)
{
    __shared__ float2 tile[256 * 17];    // 34816 B -> 4 blocks/CU (16 waves)
    const int t     = threadIdx.x;
    const int pbase = blockIdx.x * 256;

    if (pbase + 256 <= npts) {
        #pragma unroll
        for (int l = 0; l < L_LEVELS; ++l)
            tile[t * 17 + l] = ws[(size_t)l * npts + pbase + t];
        __syncthreads();

        #pragma unroll
        for (int i = 0; i < 8; ++i) {
            const int jl = i * 256 + t;          // local float4 index
            const int pl = jl >> 3;              // local point
            const int k  = jl & 7;               // float4 within point
            const float2 a = tile[pl * 17 + 2 * k];
            const float2 b = tile[pl * 17 + 2 * k + 1];
            out4[(size_t)pbase * 8 + jl] = make_float4(a.x, a.y, b.x, b.y);
        }
    } else {
        // guarded tail tile
        const int p = pbase + t;
        if (p < npts) {
            #pragma unroll
            for (int l = 0; l < L_LEVELS; ++l)
                tile[t * 17 + l] = ws[(size_t)l * npts + p];
        }
        __syncthreads();
        const int npts_loc = npts - pbase;       // valid points in tile
        for (int i = 0; i < 8; ++i) {
            const int jl = i * 256 + t;
            const int pl = jl >> 3;
            const int k  = jl & 7;
            if (pl < npts_loc) {
                const float2 a = tile[pl * 17 + 2 * k];
                const float2 b = tile[pl * 17 + 2 * k + 1];
                out4[(size_t)pbase * 8 + jl] = make_float4(a.x, a.y, b.x, b.y);
            }
        }
    }
}

// ---------------------------------------------------------------------------
// Fallback: used only if ws_size is too small for the 256MB level-major
// intermediate. One thread per (point, level), coalesced float2 output.
// ---------------------------------------------------------------------------
__global__ __launch_bounds__(256) void hash_enc_fallback(
    const float* __restrict__ x,
    const float* __restrict__ emb,
    float* __restrict__ out,
    ResArr res, int npts)
{
    __shared__ float xsh[48];
    const int tid = threadIdx.x;
    const int blockPointBase = blockIdx.x * 16;
    if (tid < 48) xsh[tid] = x[(size_t)blockPointBase * 3 + tid];
    __syncthreads();

    const int lp    = tid >> 4;
    const int level = tid & 15;
    const int p     = blockPointBase + lp;
    if (p >= npts) return;

    const float rf = (float)res.r[level];
    const float2* __restrict__ E  = (const float2*)emb + (size_t)level * T_SIZE;
    const float4* __restrict__ E4 = (const float4*)E;

    const float2 r = encode_point(xsh[lp * 3 + 0], xsh[lp * 3 + 1],
                                  xsh[lp * 3 + 2], rf, E, E4);
    ((float2*)out)[(size_t)p * 16 + level] = r;
}

extern "C" void kernel_launch(void* const* d_in, const int* in_sizes, int n_in,
                              void* d_out, int out_size, void* d_ws, size_t ws_size,
                              hipStream_t stream) {
    const float* x   = (const float*)d_in[0];
    const float* emb = (const float*)d_in[1];

    // Replicate Python: b = exp((log(2048)-log(16))/15); res_i = floor(16*b**i)
    ResArr res;
    const double b = exp((log(2048.0) - log(16.0)) / 15.0);
    for (int i = 0; i < L_LEVELS; ++i)
        res.r[i] = (int)floor(16.0 * pow(b, (double)i));

    const int npts = in_sizes[0] / 3;
    const size_t ws_needed = (size_t)npts * L_LEVELS * sizeof(float2);

    if (ws_size >= ws_needed) {
        float2* ws = (float2*)d_ws;
        const int pblocks2 = (npts + 511) / 512;
        hipLaunchKernelGGL(enc_level_kernel, dim3(pblocks2, L_LEVELS), dim3(256),
                           0, stream, x, emb, ws, res, npts);
        const int pblocks = (npts + 255) / 256;
        hipLaunchKernelGGL(transpose_tile_kernel, dim3(pblocks), dim3(256),
                           0, stream, ws, (float4*)d_out, npts);
    } else {
        const int blocks = (npts + 15) / 16;
        hipLaunchKernelGGL(hash_enc_fallback, dim3(blocks), dim3(256),
                           0, stream, x, emb, (float*)d_out, res, npts);
    }
}

// Round 6
// 1175.462 us; speedup vs baseline: 1.0310x; 1.0310x over previous
//
#include <hip/hip_runtime.h>
#include <cmath>

#define L_LEVELS 16
#define T_SIZE 524288u
#define T_MASK (T_SIZE - 1u)
#define P1 2654435761u
#define P2 805459861u

struct ResArr { int r[L_LEVELS]; };

// ---------------------------------------------------------------------------
// Per-point encode for one level.
// Slot model (calibrated R2-R4): L2 serves ~15.4 req-slots/cy/XCD;
// 8B gather = 1 slot, 16B gather ~ 1.3 slots. Corners pair over x:
// h_{j+4} = h_j ^ diffx, diffx = hx0^(hx0+1).
//   ix even (diffx==1): pair {h,h^1} = ONE aligned float4 -> 4 x 16B = 5.2
//   ix odd:             no alignment help   -> plain 8 x 8B          = 8.0
// avg 6.6 slots/point-level (round-3 code paid 7.2: odd lanes loaded the
// float4 AND the float2 partner; the unused half was wasted slot time).
// Exec-masked lanes issue no L2 requests, so the branch prunes real work.
// ---------------------------------------------------------------------------
__device__ __forceinline__ float2 encode_point(
    float px, float py, float pz, float rf,
    const float2* __restrict__ E, const float4* __restrict__ E4)
{
    // single fp32 multiplies to bit-match reference rounding
    const float sx = px * rf, sy = py * rf, sz = pz * rf;
    const int ix = (int)sx, iy = (int)sy, iz = (int)sz;  // x>=0 -> trunc==floor
    const float fx = sx - (float)ix;
    const float fy = sy - (float)iy;
    const float fz = sz - (float)iz;

    // hash keeps only low 19 bits -> uint32 arithmetic exact vs int64 reference
    const unsigned hx0 = (unsigned)ix,      hx1 = hx0 + 1u;
    const unsigned hy0 = (unsigned)iy * P1, hy1 = hy0 + P1;
    const unsigned hz0 = (unsigned)iz * P2, hz1 = hz0 + P2;
    const unsigned diffx = hx0 ^ hx1;      // 2^k-1 pattern, < 2^19 (ix<=2048)

    const unsigned h0 = (hx0 ^ hy0 ^ hz0) & T_MASK;
    const unsigned h1 = (hx0 ^ hy0 ^ hz1) & T_MASK;
    const unsigned h2 = (hx0 ^ hy1 ^ hz0) & T_MASK;
    const unsigned h3 = (hx0 ^ hy1 ^ hz1) & T_MASK;

    float2 c0v, c1v, c2v, c3v, c4v, c5v, c6v, c7v;

    if (diffx == 1u) {
        // even ix: each aligned float4 {h&~1, h|1} holds corner AND partner
        const float4 v0 = E4[h0 >> 1];
        const float4 v1 = E4[h1 >> 1];
        const float4 v2 = E4[h2 >> 1];
        const float4 v3 = E4[h3 >> 1];
        const bool o0 = (h0 & 1u), o1 = (h1 & 1u), o2 = (h2 & 1u), o3 = (h3 & 1u);
        c0v = o0 ? make_float2(v0.z, v0.w) : make_float2(v0.x, v0.y);
        c1v = o1 ? make_float2(v1.z, v1.w) : make_float2(v1.x, v1.y);
        c2v = o2 ? make_float2(v2.z, v2.w) : make_float2(v2.x, v2.y);
        c3v = o3 ? make_float2(v3.z, v3.w) : make_float2(v3.x, v3.y);
        c4v = o0 ? make_float2(v0.x, v0.y) : make_float2(v0.z, v0.w);
        c5v = o1 ? make_float2(v1.x, v1.y) : make_float2(v1.z, v1.w);
        c6v = o2 ? make_float2(v2.x, v2.y) : make_float2(v2.z, v2.w);
        c7v = o3 ? make_float2(v3.x, v3.y) : make_float2(v3.z, v3.w);
    } else {
        // odd ix: plain 8B gathers, no wasted bytes
        c0v = E[h0];
        c1v = E[h1];
        c2v = E[h2];
        c3v = E[h3];
        c4v = E[h0 ^ diffx];
        c5v = E[h1 ^ diffx];
        c6v = E[h2 ^ diffx];
        c7v = E[h3 ^ diffx];
    }

    const float gx = 1.0f - fx, gy = 1.0f - fy, gz = 1.0f - fz;
    // exact reference association: a*(1-f) + b*f
    const float c00x = c0v.x * gx + c4v.x * fx;
    const float c00y = c0v.y * gx + c4v.y * fx;
    const float c01x = c1v.x * gx + c5v.x * fx;
    const float c01y = c1v.y * gx + c5v.y * fx;
    const float c10x = c2v.x * gx + c6v.x * fx;
    const float c10y = c2v.y * gx + c6v.y * fx;
    const float c11x = c3v.x * gx + c7v.x * fx;
    const float c11y = c3v.y * gx + c7v.y * fx;

    const float a0x = c00x * gy + c10x * fy;
    const float a0y = c00y * gy + c10y * fy;
    const float a1x = c01x * gy + c11x * fy;
    const float a1y = c01y * gy + c11y * fy;

    return make_float2(a0x * gz + a1x * fz, a0y * gz + a1y * fz);
}

// ---------------------------------------------------------------------------
// K1: ONE thread per (point, level) — round-4's 2-pts/thread regressed
// (throughput-bound, not latency-bound; occupancy fell 90->66%). Reverted.
// grid = (npts/256, 16 levels), x-fastest dispatch => levels processed
// ~sequentially => each XCD's 4MB L2 holds the current level's 4MB table
// (~95% hit). ws stays level-major: full-line 512B/wave stores, no RFO
// (round-1 lesson: partial-line scatter = RFO + 4x write amplification).
// ---------------------------------------------------------------------------
__global__ __launch_bounds__(256) void enc_level_kernel(
    const float* __restrict__ x,
    const float* __restrict__ emb,
    float2* __restrict__ ws,
    ResArr res, int npts)
{
    __shared__ float xsh[768];           // 256 points * 3 coords
    const int tid   = threadIdx.x;
    const int level = blockIdx.y;
    const int pbase = blockIdx.x * 256;

    // stage x: 192 float4 loads cover 768 floats, fully coalesced
    if (pbase + 256 <= npts) {
        if (tid < 192)
            ((float4*)xsh)[tid] = ((const float4*)(x + (size_t)pbase * 3))[tid];
    } else {
        const int nfl = npts * 3 - pbase * 3;
        for (int i = tid; i < nfl; i += 256) xsh[i] = x[(size_t)pbase * 3 + i];
    }
    __syncthreads();

    const int p = pbase + tid;
    if (p >= npts) return;

    const float rf = (float)res.r[level];
    const float2* __restrict__ E  = (const float2*)emb + (size_t)level * T_SIZE;
    const float4* __restrict__ E4 = (const float4*)E;

    // lds[3t+c]: 3t mod 32 covers all banks, 2 lanes/bank -> conflict-free
    const float2 r = encode_point(xsh[tid * 3 + 0], xsh[tid * 3 + 1],
                                  xsh[tid * 3 + 2], rf, E, E4);
    ws[(size_t)level * npts + p] = r;
}

// ---------------------------------------------------------------------------
// K2: LDS-tiled transpose ws[level][point] -> out[point][level]. ~107us
// (512MB at ~4.8 TB/s effective). Near roofline; unchanged.
//   load : 16 passes, 512B/wave/instr contiguous.
//   LDS  : tile[t*17 + l] pad-17 float2 rows (write 2-way=free, read <=4-way).
//   store: 1KB/wave/instr contiguous float4, full lines, no RFO.
// ---------------------------------------------------------------------------
__global__ __launch_bounds__(256) void transpose_tile_kernel(
    const float2* __restrict__ ws, float4* __restrict__ out4, int npts)
{
    __shared__ float2 tile[256 * 17];    // 34816 B -> 4 blocks/CU (16 waves)
    const int t     = threadIdx.x;
    const int pbase = blockIdx.x * 256;

    if (pbase + 256 <= npts) {
        #pragma unroll
        for (int l = 0; l < L_LEVELS; ++l)
            tile[t * 17 + l] = ws[(size_t)l * npts + pbase + t];
        __syncthreads();

        #pragma unroll
        for (int i = 0; i < 8; ++i) {
            const int jl = i * 256 + t;          // local float4 index
            const int pl = jl >> 3;              // local point
            const int k  = jl & 7;               // float4 within point
            const float2 a = tile[pl * 17 + 2 * k];
            const float2 b = tile[pl * 17 + 2 * k + 1];
            out4[(size_t)pbase * 8 + jl] = make_float4(a.x, a.y, b.x, b.y);
        }
    } else {
        // guarded tail tile
        const int p = pbase + t;
        if (p < npts) {
            #pragma unroll
            for (int l = 0; l < L_LEVELS; ++l)
                tile[t * 17 + l] = ws[(size_t)l * npts + p];
        }
        __syncthreads();
        const int npts_loc = npts - pbase;       // valid points in tile
        for (int i = 0; i < 8; ++i) {
            const int jl = i * 256 + t;
            const int pl = jl >> 3;
            const int k  = jl & 7;
            if (pl < npts_loc) {
                const float2 a = tile[pl * 17 + 2 * k];
                const float2 b = tile[pl * 17 + 2 * k + 1];
                out4[(size_t)pbase * 8 + jl] = make_float4(a.x, a.y, b.x, b.y);
            }
        }
    }
}

// ---------------------------------------------------------------------------
// Fallback: used only if ws_size is too small for the 256MB level-major
// intermediate. One thread per (point, level), coalesced float2 output.
// ---------------------------------------------------------------------------
__global__ __launch_bounds__(256) void hash_enc_fallback(
    const float* __restrict__ x,
    const float* __restrict__ emb,
    float* __restrict__ out,
    ResArr res, int npts)
{
    __shared__ float xsh[48];
    const int tid = threadIdx.x;
    const int blockPointBase = blockIdx.x * 16;
    if (tid < 48) xsh[tid] = x[(size_t)blockPointBase * 3 + tid];
    __syncthreads();

    const int lp    = tid >> 4;
    const int level = tid & 15;
    const int p     = blockPointBase + lp;
    if (p >= npts) return;

    const float rf = (float)res.r[level];
    const float2* __restrict__ E  = (const float2*)emb + (size_t)level * T_SIZE;
    const float4* __restrict__ E4 = (const float4*)E;

    const float2 r = encode_point(xsh[lp * 3 + 0], xsh[lp * 3 + 1],
                                  xsh[lp * 3 + 2], rf, E, E4);
    ((float2*)out)[(size_t)p * 16 + level] = r;
}

extern "C" void kernel_launch(void* const* d_in, const int* in_sizes, int n_in,
                              void* d_out, int out_size, void* d_ws, size_t ws_size,
                              hipStream_t stream) {
    const float* x   = (const float*)d_in[0];
    const float* emb = (const float*)d_in[1];

    // Replicate Python: b = exp((log(2048)-log(16))/15); res_i = floor(16*b**i)
    ResArr res;
    const double b = exp((log(2048.0) - log(16.0)) / 15.0);
    for (int i = 0; i < L_LEVELS; ++i)
        res.r[i] = (int)floor(16.0 * pow(b, (double)i));

    const int npts = in_sizes[0] / 3;
    const size_t ws_needed = (size_t)npts * L_LEVELS * sizeof(float2);

    if (ws_size >= ws_needed) {
        float2* ws = (float2*)d_ws;
        const int pblocks = (npts + 255) / 256;
        hipLaunchKernelGGL(enc_level_kernel, dim3(pblocks, L_LEVELS), dim3(256),
                           0, stream, x, emb, ws, res, npts);
        hipLaunchKernelGGL(transpose_tile_kernel, dim3(pblocks), dim3(256),
                           0, stream, ws, (float4*)d_out, npts);
    } else {
        const int blocks = (npts + 15) / 16;
        hipLaunchKernelGGL(hash_enc_fallback, dim3(blocks), dim3(256),
                           0, stream, x, emb, (float*)d_out, res, npts);
    }
}

// Round 7
// 1152.499 us; speedup vs baseline: 1.0516x; 1.0199x over previous
//
#include <hip/hip_runtime.h>
#include <cmath>

#define L_LEVELS 16
#define T_SIZE 524288u
#define T_MASK (T_SIZE - 1u)
#define P1 2654435761u
#define P2 805459861u

// spatial binning for the sorted path: 5 bits/axis -> 32^3 = 32768 bins,
// ~64 points/bin at npts=2M -> one wave ~ one (1/32)^3 box.
#define NBB   5
#define NB1   (1 << NBB)           // 32
#define NBINS (1 << (3 * NBB))     // 32768

struct ResArr { int r[L_LEVELS]; };

// ---------------------------------------------------------------------------
// Per-point encode for one level.
// Slot model (calibrated R2-R6): L2 serves ~15 req-slots/cy/XCD; 8B gather
// = 1 slot, 16B gather ~1.5 slots. Corners pair over x (h_{j+4} = h_j ^
// diffx, diffx = hx0^(hx0+1)): ix even -> one aligned float4 serves both
// corners; ix odd -> plain 8B gathers. Exec-masked lanes issue no requests.
// ---------------------------------------------------------------------------
__device__ __forceinline__ float2 encode_point(
    float px, float py, float pz, float rf,
    const float2* __restrict__ E, const float4* __restrict__ E4)
{
    // single fp32 multiplies to bit-match reference rounding
    const float sx = px * rf, sy = py * rf, sz = pz * rf;
    const int ix = (int)sx, iy = (int)sy, iz = (int)sz;  // x>=0 -> trunc==floor
    const float fx = sx - (float)ix;
    const float fy = sy - (float)iy;
    const float fz = sz - (float)iz;

    // hash keeps only low 19 bits -> uint32 arithmetic exact vs int64 reference
    const unsigned hx0 = (unsigned)ix,      hx1 = hx0 + 1u;
    const unsigned hy0 = (unsigned)iy * P1, hy1 = hy0 + P1;
    const unsigned hz0 = (unsigned)iz * P2, hz1 = hz0 + P2;
    const unsigned diffx = hx0 ^ hx1;      // 2^k-1 pattern, < 2^19 (ix<=2048)

    const unsigned h0 = (hx0 ^ hy0 ^ hz0) & T_MASK;
    const unsigned h1 = (hx0 ^ hy0 ^ hz1) & T_MASK;
    const unsigned h2 = (hx0 ^ hy1 ^ hz0) & T_MASK;
    const unsigned h3 = (hx0 ^ hy1 ^ hz1) & T_MASK;

    float2 c0v, c1v, c2v, c3v, c4v, c5v, c6v, c7v;

    if (diffx == 1u) {
        // even ix: each aligned float4 {h&~1, h|1} holds corner AND partner
        const float4 v0 = E4[h0 >> 1];
        const float4 v1 = E4[h1 >> 1];
        const float4 v2 = E4[h2 >> 1];
        const float4 v3 = E4[h3 >> 1];
        const bool o0 = (h0 & 1u), o1 = (h1 & 1u), o2 = (h2 & 1u), o3 = (h3 & 1u);
        c0v = o0 ? make_float2(v0.z, v0.w) : make_float2(v0.x, v0.y);
        c1v = o1 ? make_float2(v1.z, v1.w) : make_float2(v1.x, v1.y);
        c2v = o2 ? make_float2(v2.z, v2.w) : make_float2(v2.x, v2.y);
        c3v = o3 ? make_float2(v3.z, v3.w) : make_float2(v3.x, v3.y);
        c4v = o0 ? make_float2(v0.x, v0.y) : make_float2(v0.z, v0.w);
        c5v = o1 ? make_float2(v1.x, v1.y) : make_float2(v1.z, v1.w);
        c6v = o2 ? make_float2(v2.x, v2.y) : make_float2(v2.z, v2.w);
        c7v = o3 ? make_float2(v3.x, v3.y) : make_float2(v3.z, v3.w);
    } else {
        // odd ix: plain 8B gathers, no wasted bytes
        c0v = E[h0];
        c1v = E[h1];
        c2v = E[h2];
        c3v = E[h3];
        c4v = E[h0 ^ diffx];
        c5v = E[h1 ^ diffx];
        c6v = E[h2 ^ diffx];
        c7v = E[h3 ^ diffx];
    }

    const float gx = 1.0f - fx, gy = 1.0f - fy, gz = 1.0f - fz;
    // exact reference association: a*(1-f) + b*f
    const float c00x = c0v.x * gx + c4v.x * fx;
    const float c00y = c0v.y * gx + c4v.y * fx;
    const float c01x = c1v.x * gx + c5v.x * fx;
    const float c01y = c1v.y * gx + c5v.y * fx;
    const float c10x = c2v.x * gx + c6v.x * fx;
    const float c10y = c2v.y * gx + c6v.y * fx;
    const float c11x = c3v.x * gx + c7v.x * fx;
    const float c11y = c3v.y * gx + c7v.y * fx;

    const float a0x = c00x * gy + c10x * fy;
    const float a0y = c00y * gy + c10y * fy;
    const float a1x = c01x * gy + c11x * fy;
    const float a1y = c01y * gy + c11y * fy;

    return make_float2(a0x * gz + a1x * fz, a0y * gz + a1y * fz);
}

__device__ __forceinline__ unsigned bin_key(float px, float py, float pz)
{
    int bx = (int)(px * (float)NB1); bx = bx > NB1 - 1 ? NB1 - 1 : bx;
    int by = (int)(py * (float)NB1); by = by > NB1 - 1 ? NB1 - 1 : by;
    int bz = (int)(pz * (float)NB1); bz = bz > NB1 - 1 ? NB1 - 1 : bz;
    // x innermost: consecutive bins are x-adjacent boxes (corner overlap)
    return (((unsigned)bz << NBB | (unsigned)by) << NBB) | (unsigned)bx;
}

// ---------------------------------------------------------------------------
// S1: bin histogram. 2M atomics over 32768 counters (~64/bin) - L2 atomic
// throughput makes this ~10us. One coalesced pass over x.
// ---------------------------------------------------------------------------
__global__ __launch_bounds__(256) void hist_kernel(
    const float* __restrict__ x, unsigned* __restrict__ hist, int npts)
{
    int i = blockIdx.x * 256 + threadIdx.x;
    const int stride = gridDim.x * 256;
    for (; i < npts; i += stride) {
        const size_t b = (size_t)i * 3;
        atomicAdd(&hist[bin_key(x[b], x[b + 1], x[b + 2])], 1u);
    }
}

// ---------------------------------------------------------------------------
// S2: exclusive scan of 32768 counters, single 1024-thread block.
// ---------------------------------------------------------------------------
__global__ __launch_bounds__(1024) void scan_kernel(unsigned* __restrict__ hist)
{
    __shared__ unsigned part[1024];
    const int t = threadIdx.x;
    unsigned v[NBINS / 1024];
    unsigned s = 0;
    #pragma unroll
    for (int j = 0; j < NBINS / 1024; ++j) { v[j] = hist[t * (NBINS / 1024) + j]; s += v[j]; }
    part[t] = s;
    __syncthreads();
    if (t == 0) {
        unsigned run = 0;
        for (int i = 0; i < 1024; ++i) { const unsigned tmp = part[i]; part[i] = run; run += tmp; }
    }
    __syncthreads();
    unsigned run = part[t];
    #pragma unroll
    for (int j = 0; j < NBINS / 1024; ++j) { const unsigned tmp = v[j]; hist[t * (NBINS / 1024) + j] = run; run += tmp; }
}

// ---------------------------------------------------------------------------
// S3: scatter points into bin order. xs4[dest] = (x,y,z, bits(orig_idx)).
// cursor = scanned hist, consumed via atomicAdd (rebuilt every launch).
// ---------------------------------------------------------------------------
__global__ __launch_bounds__(256) void scatter_kernel(
    const float* __restrict__ x, unsigned* __restrict__ cursor,
    float4* __restrict__ xs4, int npts)
{
    __shared__ float xsh[768];
    const int tid = threadIdx.x, pbase = blockIdx.x * 256;
    if (pbase + 256 <= npts) {
        if (tid < 192)
            ((float4*)xsh)[tid] = ((const float4*)(x + (size_t)pbase * 3))[tid];
    } else {
        const int nfl = npts * 3 - pbase * 3;
        for (int i = tid; i < nfl; i += 256) xsh[i] = x[(size_t)pbase * 3 + i];
    }
    __syncthreads();
    const int p = pbase + tid;
    if (p >= npts) return;
    const float px = xsh[tid * 3], py = xsh[tid * 3 + 1], pz = xsh[tid * 3 + 2];
    const unsigned dest = atomicAdd(&cursor[bin_key(px, py, pz)], 1u);
    xs4[dest] = make_float4(px, py, pz, __uint_as_float((unsigned)p));
}

// ---------------------------------------------------------------------------
// K1 (sorted): one thread per (sorted point, level); grid (npts/256, 16),
// x-fastest => level-sequential => each XCD L2 holds the current 4MB table.
// Sorted order => a wave's 64 points share a ~(1/32)^3 box => at low levels
// the corner gathers hit few distinct lines and the TA merges same-line
// lanes into one L2 request. No LDS, no barrier (coalesced float4 x-load).
// ws stays level-major: full-line 512B/wave stores, no RFO (round-1 lesson).
// ---------------------------------------------------------------------------
__global__ __launch_bounds__(256) void enc_level_sorted(
    const float4* __restrict__ xs4,
    const float* __restrict__ emb,
    float2* __restrict__ ws,
    ResArr res, int npts)
{
    const int level = blockIdx.y;
    const int p = blockIdx.x * 256 + threadIdx.x;
    if (p >= npts) return;
    const float4 q = xs4[p];
    const float rf = (float)res.r[level];
    const float2* __restrict__ E  = (const float2*)emb + (size_t)level * T_SIZE;
    const float4* __restrict__ E4 = (const float4*)E;
    ws[(size_t)level * npts + p] = encode_point(q.x, q.y, q.z, rf, E, E4);
}

// ---------------------------------------------------------------------------
// K2 (sorted): transpose ws[level][sorted] -> out[orig][level] and unpermute.
// Loads stay fully coalesced (sorted index). Store phase: 4 consecutive
// lanes cooperate on one point's 128B row => each store instruction writes
// full 64B lines (16 rows x 64B per wave-instr) at scattered row addresses
// => no RFO, no partial-line amplification (round-1 lesson).
// ---------------------------------------------------------------------------
__global__ __launch_bounds__(256) void transpose_unperm_kernel(
    const float2* __restrict__ ws, const float4* __restrict__ xs4,
    float4* __restrict__ out4, int npts)
{
    __shared__ float2 tile[256 * 17];    // pad-17: load-phase write 2-way=free
    __shared__ unsigned pidx[256];
    const int t = threadIdx.x, pbase = blockIdx.x * 256;

    if (pbase + 256 <= npts) {
        #pragma unroll
        for (int l = 0; l < L_LEVELS; ++l)
            tile[t * 17 + l] = ws[(size_t)l * npts + pbase + t];
        pidx[t] = __float_as_uint(((const float*)xs4)[4 * (size_t)(pbase + t) + 3]);
        __syncthreads();

        #pragma unroll
        for (int pass = 0; pass < 4; ++pass) {
            const int pl = pass * 64 + (t >> 2);   // local point, 4 lanes each
            const int qd = t & 3;                  // 16B quarter of a 64B line
            const size_t prow = (size_t)pidx[pl];
            #pragma unroll
            for (int half = 0; half < 2; ++half) { // row = 128B = 2 lines
                const int chunk = half * 4 + qd;   // float4 index within row
                const float2 a = tile[pl * 17 + 2 * chunk];
                const float2 b = tile[pl * 17 + 2 * chunk + 1];
                out4[prow * 8 + chunk] = make_float4(a.x, a.y, b.x, b.y);
            }
        }
    } else {
        const int p = pbase + t;
        if (p < npts) {
            #pragma unroll
            for (int l = 0; l < L_LEVELS; ++l)
                tile[t * 17 + l] = ws[(size_t)l * npts + p];
            pidx[t] = __float_as_uint(((const float*)xs4)[4 * (size_t)p + 3]);
        }
        __syncthreads();
        if (p < npts) {
            const size_t prow = (size_t)pidx[t];
            for (int k = 0; k < 8; ++k) {
                const float2 a = tile[t * 17 + 2 * k];
                const float2 b = tile[t * 17 + 2 * k + 1];
                out4[prow * 8 + k] = make_float4(a.x, a.y, b.x, b.y);
            }
        }
    }
}

// ---------------------------------------------------------------------------
// R6 path (kept as fallback if ws can't fit the sort buffers): unsorted K1.
// ---------------------------------------------------------------------------
__global__ __launch_bounds__(256) void enc_level_kernel(
    const float* __restrict__ x,
    const float* __restrict__ emb,
    float2* __restrict__ ws,
    ResArr res, int npts)
{
    __shared__ float xsh[768];
    const int tid   = threadIdx.x;
    const int level = blockIdx.y;
    const int pbase = blockIdx.x * 256;

    if (pbase + 256 <= npts) {
        if (tid < 192)
            ((float4*)xsh)[tid] = ((const float4*)(x + (size_t)pbase * 3))[tid];
    } else {
        const int nfl = npts * 3 - pbase * 3;
        for (int i = tid; i < nfl; i += 256) xsh[i] = x[(size_t)pbase * 3 + i];
    }
    __syncthreads();

    const int p = pbase + tid;
    if (p >= npts) return;

    const float rf = (float)res.r[level];
    const float2* __restrict__ E  = (const float2*)emb + (size_t)level * T_SIZE;
    const float4* __restrict__ E4 = (const float4*)E;

    const float2 r = encode_point(xsh[tid * 3 + 0], xsh[tid * 3 + 1],
                                  xsh[tid * 3 + 2], rf, E, E4);
    ws[(size_t)level * npts + p] = r;
}

__global__ __launch_bounds__(256) void transpose_tile_kernel(
    const float2* __restrict__ ws, float4* __restrict__ out4, int npts)
{
    __shared__ float2 tile[256 * 17];
    const int t     = threadIdx.x;
    const int pbase = blockIdx.x * 256;

    if (pbase + 256 <= npts) {
        #pragma unroll
        for (int l = 0; l < L_LEVELS; ++l)
            tile[t * 17 + l] = ws[(size_t)l * npts + pbase + t];
        __syncthreads();
        #pragma unroll
        for (int i = 0; i < 8; ++i) {
            const int jl = i * 256 + t;
            const int pl = jl >> 3;
            const int k  = jl & 7;
            const float2 a = tile[pl * 17 + 2 * k];
            const float2 b = tile[pl * 17 + 2 * k + 1];
            out4[(size_t)pbase * 8 + jl] = make_float4(a.x, a.y, b.x, b.y);
        }
    } else {
        const int p = pbase + t;
        if (p < npts) {
            #pragma unroll
            for (int l = 0; l < L_LEVELS; ++l)
                tile[t * 17 + l] = ws[(size_t)l * npts + p];
        }
        __syncthreads();
        const int npts_loc = npts - pbase;
        for (int i = 0; i < 8; ++i) {
            const int jl = i * 256 + t;
            const int pl = jl >> 3;
            const int k  = jl & 7;
            if (pl < npts_loc) {
                const float2 a = tile[pl * 17 + 2 * k];
                const float2 b = tile[pl * 17 + 2 * k + 1];
                out4[(size_t)pbase * 8 + jl] = make_float4(a.x, a.y, b.x, b.y);
            }
        }
    }
}

// ---------------------------------------------------------------------------
// Last-resort fallback: tiny ws. One thread per (point, level).
// ---------------------------------------------------------------------------
__global__ __launch_bounds__(256) void hash_enc_fallback(
    const float* __restrict__ x,
    const float* __restrict__ emb,
    float* __restrict__ out,
    ResArr res, int npts)
{
    __shared__ float xsh[48];
    const int tid = threadIdx.x;
    const int blockPointBase = blockIdx.x * 16;
    if (tid < 48) xsh[tid] = x[(size_t)blockPointBase * 3 + tid];
    __syncthreads();

    const int lp    = tid >> 4;
    const int level = tid & 15;
    const int p     = blockPointBase + lp;
    if (p >= npts) return;

    const float rf = (float)res.r[level];
    const float2* __restrict__ E  = (const float2*)emb + (size_t)level * T_SIZE;
    const float4* __restrict__ E4 = (const float4*)E;

    const float2 r = encode_point(xsh[lp * 3 + 0], xsh[lp * 3 + 1],
                                  xsh[lp * 3 + 2], rf, E, E4);
    ((float2*)out)[(size_t)p * 16 + level] = r;
}

extern "C" void kernel_launch(void* const* d_in, const int* in_sizes, int n_in,
                              void* d_out, int out_size, void* d_ws, size_t ws_size,
                              hipStream_t stream) {
    const float* x   = (const float*)d_in[0];
    const float* emb = (const float*)d_in[1];

    // Replicate Python: b = exp((log(2048)-log(16))/15); res_i = floor(16*b**i)
    ResArr res;
    const double b = exp((log(2048.0) - log(16.0)) / 15.0);
    for (int i = 0; i < L_LEVELS; ++i)
        res.r[i] = (int)floor(16.0 * pow(b, (double)i));

    const int npts = in_sizes[0] / 3;
    const int pblocks = (npts + 255) / 256;

    const size_t ws2_bytes  = (size_t)npts * L_LEVELS * sizeof(float2);
    const size_t xs4_bytes  = (size_t)npts * sizeof(float4);
    const size_t hist_bytes = (size_t)NBINS * sizeof(unsigned);
    const size_t need_sorted = ws2_bytes + xs4_bytes + hist_bytes;

    if (ws_size >= need_sorted) {
        float2*   ws2  = (float2*)d_ws;
        float4*   xs4  = (float4*)((char*)d_ws + ws2_bytes);
        unsigned* hist = (unsigned*)((char*)d_ws + ws2_bytes + xs4_bytes);

        hipMemsetAsync(hist, 0, hist_bytes, stream);
        hipLaunchKernelGGL(hist_kernel, dim3(2048), dim3(256), 0, stream,
                           x, hist, npts);
        hipLaunchKernelGGL(scan_kernel, dim3(1), dim3(1024), 0, stream, hist);
        hipLaunchKernelGGL(scatter_kernel, dim3(pblocks), dim3(256), 0, stream,
                           x, hist, xs4, npts);
        hipLaunchKernelGGL(enc_level_sorted, dim3(pblocks, L_LEVELS), dim3(256),
                           0, stream, xs4, emb, ws2, res, npts);
        hipLaunchKernelGGL(transpose_unperm_kernel, dim3(pblocks), dim3(256),
                           0, stream, ws2, xs4, (float4*)d_out, npts);
    } else if (ws_size >= ws2_bytes) {
        float2* ws = (float2*)d_ws;
        hipLaunchKernelGGL(enc_level_kernel, dim3(pblocks, L_LEVELS), dim3(256),
                           0, stream, x, emb, ws, res, npts);
        hipLaunchKernelGGL(transpose_tile_kernel, dim3(pblocks), dim3(256),
                           0, stream, ws, (float4*)d_out, npts);
    } else {
        const int blocks = (npts + 15) / 16;
        hipLaunchKernelGGL(hash_enc_fallback, dim3(blocks), dim3(256),
                           0, stream, x, emb, (float*)d_out, res, npts);
    }
}

// Round 8
// 1119.333 us; speedup vs baseline: 1.0827x; 1.0296x over previous
//
#include <hip/hip_runtime.h>
#include <cmath>

#define L_LEVELS 16
#define T_SIZE 524288u
#define T_MASK (T_SIZE - 1u)
#define P1 2654435761u
#define P2 805459861u

// spatial binning: 5 bits/axis -> 32^3 bins, ~64 pts/bin at 2M pts -> one
// wave ~ one (1/32)^3 box. (NBB=6 elongates the wave box in x -> worse at
// mid levels; NBB=4 puts 8 waves per box -> worse merge. 5 is the sweet spot.)
#define NBB   5
#define NB1   (1 << NBB)           // 32
#define NBINS (1 << (3 * NBB))     // 32768

struct ResArr { int r[L_LEVELS]; };
typedef float f32x4 __attribute__((ext_vector_type(4)));

// ---------------------------------------------------------------------------
// Per-point encode for one level.
// Slot model (calibrated R2-R7): L2 serves ~15 req-slots/cy/XCD; request
// count = sum over instructions of distinct lines touched by active lanes
// (cross-lane same-line merge happens per instruction -> sorting pays;
// cross-instruction hits still cost a slot). ix even: one aligned float4
// serves both x-paired corners; ix odd: plain 8B gathers.
// ---------------------------------------------------------------------------
__device__ __forceinline__ float2 encode_point(
    float px, float py, float pz, float rf,
    const float2* __restrict__ E, const float4* __restrict__ E4)
{
    // single fp32 multiplies to bit-match reference rounding
    const float sx = px * rf, sy = py * rf, sz = pz * rf;
    const int ix = (int)sx, iy = (int)sy, iz = (int)sz;  // x>=0 -> trunc==floor
    const float fx = sx - (float)ix;
    const float fy = sy - (float)iy;
    const float fz = sz - (float)iz;

    // hash keeps only low 19 bits -> uint32 arithmetic exact vs int64 reference
    const unsigned hx0 = (unsigned)ix,      hx1 = hx0 + 1u;
    const unsigned hy0 = (unsigned)iy * P1, hy1 = hy0 + P1;
    const unsigned hz0 = (unsigned)iz * P2, hz1 = hz0 + P2;
    const unsigned diffx = hx0 ^ hx1;      // 2^k-1 pattern, < 2^19 (ix<=2048)

    const unsigned h0 = (hx0 ^ hy0 ^ hz0) & T_MASK;
    const unsigned h1 = (hx0 ^ hy0 ^ hz1) & T_MASK;
    const unsigned h2 = (hx0 ^ hy1 ^ hz0) & T_MASK;
    const unsigned h3 = (hx0 ^ hy1 ^ hz1) & T_MASK;

    float2 c0v, c1v, c2v, c3v, c4v, c5v, c6v, c7v;

    if (diffx == 1u) {
        // even ix: each aligned float4 {h&~1, h|1} holds corner AND partner
        const float4 v0 = E4[h0 >> 1];
        const float4 v1 = E4[h1 >> 1];
        const float4 v2 = E4[h2 >> 1];
        const float4 v3 = E4[h3 >> 1];
        const bool o0 = (h0 & 1u), o1 = (h1 & 1u), o2 = (h2 & 1u), o3 = (h3 & 1u);
        c0v = o0 ? make_float2(v0.z, v0.w) : make_float2(v0.x, v0.y);
        c1v = o1 ? make_float2(v1.z, v1.w) : make_float2(v1.x, v1.y);
        c2v = o2 ? make_float2(v2.z, v2.w) : make_float2(v2.x, v2.y);
        c3v = o3 ? make_float2(v3.z, v3.w) : make_float2(v3.x, v3.y);
        c4v = o0 ? make_float2(v0.x, v0.y) : make_float2(v0.z, v0.w);
        c5v = o1 ? make_float2(v1.x, v1.y) : make_float2(v1.z, v1.w);
        c6v = o2 ? make_float2(v2.x, v2.y) : make_float2(v2.z, v2.w);
        c7v = o3 ? make_float2(v3.x, v3.y) : make_float2(v3.z, v3.w);
    } else {
        // odd ix: plain 8B gathers, no wasted bytes
        c0v = E[h0];
        c1v = E[h1];
        c2v = E[h2];
        c3v = E[h3];
        c4v = E[h0 ^ diffx];
        c5v = E[h1 ^ diffx];
        c6v = E[h2 ^ diffx];
        c7v = E[h3 ^ diffx];
    }

    const float gx = 1.0f - fx, gy = 1.0f - fy, gz = 1.0f - fz;
    // exact reference association: a*(1-f) + b*f
    const float c00x = c0v.x * gx + c4v.x * fx;
    const float c00y = c0v.y * gx + c4v.y * fx;
    const float c01x = c1v.x * gx + c5v.x * fx;
    const float c01y = c1v.y * gx + c5v.y * fx;
    const float c10x = c2v.x * gx + c6v.x * fx;
    const float c10y = c2v.y * gx + c6v.y * fx;
    const float c11x = c3v.x * gx + c7v.x * fx;
    const float c11y = c3v.y * gx + c7v.y * fx;

    const float a0x = c00x * gy + c10x * fy;
    const float a0y = c00y * gy + c10y * fy;
    const float a1x = c01x * gy + c11x * fy;
    const float a1y = c01y * gy + c11y * fy;

    return make_float2(a0x * gz + a1x * fz, a0y * gz + a1y * fz);
}

__device__ __forceinline__ unsigned bin_key(float px, float py, float pz)
{
    int bx = (int)(px * (float)NB1); bx = bx > NB1 - 1 ? NB1 - 1 : bx;
    int by = (int)(py * (float)NB1); by = by > NB1 - 1 ? NB1 - 1 : by;
    int bz = (int)(pz * (float)NB1); bz = bz > NB1 - 1 ? NB1 - 1 : bz;
    // x innermost: consecutive bins are x-adjacent boxes (corner overlap)
    return (((unsigned)bz << NBB | (unsigned)by) << NBB) | (unsigned)bx;
}

// ---------------------------------------------------------------------------
// S1: bin histogram. 2M atomics over 32768 L2 counters, ~15us.
// ---------------------------------------------------------------------------
__global__ __launch_bounds__(256) void hist_kernel(
    const float* __restrict__ x, unsigned* __restrict__ hist, int npts)
{
    int i = blockIdx.x * 256 + threadIdx.x;
    const int stride = gridDim.x * 256;
    for (; i < npts; i += stride) {
        const size_t b = (size_t)i * 3;
        atomicAdd(&hist[bin_key(x[b], x[b + 1], x[b + 2])], 1u);
    }
}

// ---------------------------------------------------------------------------
// S2: exclusive scan of 32768 counters, single 1024-thread block.
// Round-8: fully parallel (R7 version serialized 1024 iters on thread 0).
// Per-thread 32-chunk sum -> wave shfl-scan -> cross-wave scan -> writeback.
// ---------------------------------------------------------------------------
__global__ __launch_bounds__(1024) void scan_kernel(unsigned* __restrict__ hist)
{
    __shared__ unsigned wsum[16];        // 1024 threads = 16 waves
    const int t = threadIdx.x;
    const int CH = NBINS / 1024;         // 32
    unsigned v[NBINS / 1024];
    unsigned s = 0;
    #pragma unroll
    for (int j = 0; j < CH; ++j) { v[j] = hist[t * CH + j]; s += v[j]; }

    // inclusive scan of s within the wave
    unsigned inc = s;
    #pragma unroll
    for (int d = 1; d < 64; d <<= 1) {
        const unsigned n = __shfl_up(inc, d, 64);
        if ((t & 63) >= d) inc += n;
    }
    const int wave = t >> 6;
    if ((t & 63) == 63) wsum[wave] = inc;
    __syncthreads();
    if (wave == 0) {
        const unsigned w = (t < 16) ? wsum[t] : 0u;
        unsigned winc = w;
        #pragma unroll
        for (int d = 1; d < 16; d <<= 1) {
            const unsigned n = __shfl_up(winc, d, 64);
            if (t >= d) winc += n;
        }
        if (t < 16) wsum[t] = winc - w;  // exclusive wave offset
    }
    __syncthreads();

    unsigned run = wsum[wave] + (inc - s);   // global exclusive prefix
    #pragma unroll
    for (int j = 0; j < CH; ++j) { const unsigned tmp = v[j]; hist[t * CH + j] = run; run += tmp; }
}

// ---------------------------------------------------------------------------
// S3: scatter points into bin order. xs4[dest] = (x,y,z, bits(orig_idx)).
// cursor = scanned hist, consumed via atomicAdd (rebuilt every launch).
// xs4 stores stay CACHED (read 16x by enc; L3-resident 32MB).
// ---------------------------------------------------------------------------
__global__ __launch_bounds__(256) void scatter_kernel(
    const float* __restrict__ x, unsigned* __restrict__ cursor,
    float4* __restrict__ xs4, int npts)
{
    __shared__ float xsh[768];
    const int tid = threadIdx.x, pbase = blockIdx.x * 256;
    if (pbase + 256 <= npts) {
        if (tid < 192)
            ((float4*)xsh)[tid] = ((const float4*)(x + (size_t)pbase * 3))[tid];
    } else {
        const int nfl = npts * 3 - pbase * 3;
        for (int i = tid; i < nfl; i += 256) xsh[i] = x[(size_t)pbase * 3 + i];
    }
    __syncthreads();
    const int p = pbase + tid;
    if (p >= npts) return;
    const float px = xsh[tid * 3], py = xsh[tid * 3 + 1], pz = xsh[tid * 3 + 2];
    const unsigned dest = atomicAdd(&cursor[bin_key(px, py, pz)], 1u);
    xs4[dest] = make_float4(px, py, pz, __uint_as_float((unsigned)p));
}

// ---------------------------------------------------------------------------
// K1 (sorted): one thread per (sorted point, level); grid (npts/256, 16),
// x-fastest => level-sequential => each XCD L2 holds the current 4MB table.
// Sorted order => wave's 64 points share a (1/32)^3 box => low/mid-level
// corner gathers TA-merge into few line requests (enc 842 -> 543us, R7).
// Round-8: ws stores NONTEMPORAL — ws is write-once/read-once and exactly
// L3-sized; NT keeps L3 reserved for the 64MB of tables + 32MB xs4.
// (Round-1 lesson intact: full-line 512B/wave stores, no RFO.)
// ---------------------------------------------------------------------------
__global__ __launch_bounds__(256) void enc_level_sorted(
    const float4* __restrict__ xs4,
    const float* __restrict__ emb,
    float2* __restrict__ ws,
    ResArr res, int npts)
{
    const int level = blockIdx.y;
    const int p = blockIdx.x * 256 + threadIdx.x;
    if (p >= npts) return;
    const float4 q = xs4[p];
    const float rf = (float)res.r[level];
    const float2* __restrict__ E  = (const float2*)emb + (size_t)level * T_SIZE;
    const float4* __restrict__ E4 = (const float4*)E;
    const float2 r = encode_point(q.x, q.y, q.z, rf, E, E4);
    union { float2 f2; double d; } u; u.f2 = r;
    __builtin_nontemporal_store(u.d, (double*)&ws[(size_t)level * npts + p]);
}

// ---------------------------------------------------------------------------
// K2 (sorted): transpose ws[level][sorted] -> out[orig][level] + unpermute.
// Round-8 changes (R7 unperm ~290us, stores = 16 scattered 64B lines/instr):
//   - store lane-map 8 lanes/row: each wave-instr writes 8 CONTIGUOUS 128B
//     extents (full output rows) -> double the DRAM extent size.
//   - NT loads on ws (read-once), NT stores on out (write-once): neither
//     allocates in L3, preserving it for enc's tables.
// Loads unchanged: 16 passes, 512B/wave/instr contiguous, pad-17 LDS tile.
// ---------------------------------------------------------------------------
__global__ __launch_bounds__(256) void transpose_unperm_kernel(
    const float2* __restrict__ ws, const float4* __restrict__ xs4,
    float4* __restrict__ out4, int npts)
{
    __shared__ float2 tile[256 * 17];    // 34816B + 1KB pidx -> 4 blocks/CU
    __shared__ unsigned pidx[256];
    const int t = threadIdx.x, pbase = blockIdx.x * 256;
    const double* __restrict__ wsd = (const double*)ws;

    if (pbase + 256 <= npts) {
        #pragma unroll
        for (int l = 0; l < L_LEVELS; ++l) {
            const double tmp =
                __builtin_nontemporal_load(&wsd[(size_t)l * npts + pbase + t]);
            *(double*)&tile[t * 17 + l] = tmp;
        }
        pidx[t] = __float_as_uint(((const float*)xs4)[4 * (size_t)(pbase + t) + 3]);
        __syncthreads();

        #pragma unroll
        for (int pass = 0; pass < 8; ++pass) {
            const int r = pass * 32 + (t >> 3);  // local row (point)
            const int q = t & 7;                 // float4 within 128B row
            const size_t prow = (size_t)pidx[r];
            const float2 a = tile[r * 17 + 2 * q];
            const float2 b = tile[r * 17 + 2 * q + 1];
            f32x4 v; v.x = a.x; v.y = a.y; v.z = b.x; v.w = b.y;
            __builtin_nontemporal_store(v, (f32x4*)&out4[prow * 8 + q]);
        }
    } else {
        const int p = pbase + t;
        if (p < npts) {
            #pragma unroll
            for (int l = 0; l < L_LEVELS; ++l)
                tile[t * 17 + l] = ws[(size_t)l * npts + p];
            pidx[t] = __float_as_uint(((const float*)xs4)[4 * (size_t)p + 3]);
        }
        __syncthreads();
        if (p < npts) {
            const size_t prow = (size_t)pidx[t];
            for (int k = 0; k < 8; ++k) {
                const float2 a = tile[t * 17 + 2 * k];
                const float2 b = tile[t * 17 + 2 * k + 1];
                out4[prow * 8 + k] = make_float4(a.x, a.y, b.x, b.y);
            }
        }
    }
}

// ---------------------------------------------------------------------------
// R6 path (fallback if ws can't fit the sort buffers): unsorted K1 + K2.
// ---------------------------------------------------------------------------
__global__ __launch_bounds__(256) void enc_level_kernel(
    const float* __restrict__ x,
    const float* __restrict__ emb,
    float2* __restrict__ ws,
    ResArr res, int npts)
{
    __shared__ float xsh[768];
    const int tid   = threadIdx.x;
    const int level = blockIdx.y;
    const int pbase = blockIdx.x * 256;

    if (pbase + 256 <= npts) {
        if (tid < 192)
            ((float4*)xsh)[tid] = ((const float4*)(x + (size_t)pbase * 3))[tid];
    } else {
        const int nfl = npts * 3 - pbase * 3;
        for (int i = tid; i < nfl; i += 256) xsh[i] = x[(size_t)pbase * 3 + i];
    }
    __syncthreads();

    const int p = pbase + tid;
    if (p >= npts) return;

    const float rf = (float)res.r[level];
    const float2* __restrict__ E  = (const float2*)emb + (size_t)level * T_SIZE;
    const float4* __restrict__ E4 = (const float4*)E;

    const float2 r = encode_point(xsh[tid * 3 + 0], xsh[tid * 3 + 1],
                                  xsh[tid * 3 + 2], rf, E, E4);
    ws[(size_t)level * npts + p] = r;
}

__global__ __launch_bounds__(256) void transpose_tile_kernel(
    const float2* __restrict__ ws, float4* __restrict__ out4, int npts)
{
    __shared__ float2 tile[256 * 17];
    const int t     = threadIdx.x;
    const int pbase = blockIdx.x * 256;

    if (pbase + 256 <= npts) {
        #pragma unroll
        for (int l = 0; l < L_LEVELS; ++l)
            tile[t * 17 + l] = ws[(size_t)l * npts + pbase + t];
        __syncthreads();
        #pragma unroll
        for (int i = 0; i < 8; ++i) {
            const int jl = i * 256 + t;
            const int pl = jl >> 3;
            const int k  = jl & 7;
            const float2 a = tile[pl * 17 + 2 * k];
            const float2 b = tile[pl * 17 + 2 * k + 1];
            out4[(size_t)pbase * 8 + jl] = make_float4(a.x, a.y, b.x, b.y);
        }
    } else {
        const int p = pbase + t;
        if (p < npts) {
            #pragma unroll
            for (int l = 0; l < L_LEVELS; ++l)
                tile[t * 17 + l] = ws[(size_t)l * npts + p];
        }
        __syncthreads();
        const int npts_loc = npts - pbase;
        for (int i = 0; i < 8; ++i) {
            const int jl = i * 256 + t;
            const int pl = jl >> 3;
            const int k  = jl & 7;
            if (pl < npts_loc) {
                const float2 a = tile[pl * 17 + 2 * k];
                const float2 b = tile[pl * 17 + 2 * k + 1];
                out4[(size_t)pbase * 8 + jl] = make_float4(a.x, a.y, b.x, b.y);
            }
        }
    }
}

// ---------------------------------------------------------------------------
// Last-resort fallback: tiny ws. One thread per (point, level).
// ---------------------------------------------------------------------------
__global__ __launch_bounds__(256) void hash_enc_fallback(
    const float* __restrict__ x,
    const float* __restrict__ emb,
    float* __restrict__ out,
    ResArr res, int npts)
{
    __shared__ float xsh[48];
    const int tid = threadIdx.x;
    const int blockPointBase = blockIdx.x * 16;
    if (tid < 48) xsh[tid] = x[(size_t)blockPointBase * 3 + tid];
    __syncthreads();

    const int lp    = tid >> 4;
    const int level = tid & 15;
    const int p     = blockPointBase + lp;
    if (p >= npts) return;

    const float rf = (float)res.r[level];
    const float2* __restrict__ E  = (const float2*)emb + (size_t)level * T_SIZE;
    const float4* __restrict__ E4 = (const float4*)E;

    const float2 r = encode_point(xsh[lp * 3 + 0], xsh[lp * 3 + 1],
                                  xsh[lp * 3 + 2], rf, E, E4);
    ((float2*)out)[(size_t)p * 16 + level] = r;
}

extern "C" void kernel_launch(void* const* d_in, const int* in_sizes, int n_in,
                              void* d_out, int out_size, void* d_ws, size_t ws_size,
                              hipStream_t stream) {
    const float* x   = (const float*)d_in[0];
    const float* emb = (const float*)d_in[1];

    // Replicate Python: b = exp((log(2048)-log(16))/15); res_i = floor(16*b**i)
    ResArr res;
    const double b = exp((log(2048.0) - log(16.0)) / 15.0);
    for (int i = 0; i < L_LEVELS; ++i)
        res.r[i] = (int)floor(16.0 * pow(b, (double)i));

    const int npts = in_sizes[0] / 3;
    const int pblocks = (npts + 255) / 256;

    const size_t ws2_bytes  = (size_t)npts * L_LEVELS * sizeof(float2);
    const size_t xs4_bytes  = (size_t)npts * sizeof(float4);
    const size_t hist_bytes = (size_t)NBINS * sizeof(unsigned);
    const size_t need_sorted = ws2_bytes + xs4_bytes + hist_bytes;

    if (ws_size >= need_sorted) {
        float2*   ws2  = (float2*)d_ws;
        float4*   xs4  = (float4*)((char*)d_ws + ws2_bytes);
        unsigned* hist = (unsigned*)((char*)d_ws + ws2_bytes + xs4_bytes);

        hipMemsetAsync(hist, 0, hist_bytes, stream);
        hipLaunchKernelGGL(hist_kernel, dim3(2048), dim3(256), 0, stream,
                           x, hist, npts);
        hipLaunchKernelGGL(scan_kernel, dim3(1), dim3(1024), 0, stream, hist);
        hipLaunchKernelGGL(scatter_kernel, dim3(pblocks), dim3(256), 0, stream,
                           x, hist, xs4, npts);
        hipLaunchKernelGGL(enc_level_sorted, dim3(pblocks, L_LEVELS), dim3(256),
                           0, stream, xs4, emb, ws2, res, npts);
        hipLaunchKernelGGL(transpose_unperm_kernel, dim3(pblocks), dim3(256),
                           0, stream, ws2, xs4, (float4*)d_out, npts);
    } else if (ws_size >= ws2_bytes) {
        float2* ws = (float2*)d_ws;
        hipLaunchKernelGGL(enc_level_kernel, dim3(pblocks, L_LEVELS), dim3(256),
                           0, stream, x, emb, ws, res, npts);
        hipLaunchKernelGGL(transpose_tile_kernel, dim3(pblocks), dim3(256),
                           0, stream, ws, (float4*)d_out, npts);
    } else {
        const int blocks = (npts + 15) / 16;
        hipLaunchKernelGGL(hash_enc_fallback, dim3(blocks), dim3(256),
                           0, stream, x, emb, (float*)d_out, res, npts);
    }
}

// Round 9
// 1050.721 us; speedup vs baseline: 1.1534x; 1.0653x over previous
//
#include <hip/hip_runtime.h>
#include <cmath>

#define L_LEVELS 16
#define LSPLIT   8                 // levels [0,LSPLIT) recomputed in unperm;
                                   // levels [LSPLIT,16) via ws two-pass
#define T_SIZE 524288u
#define T_MASK (T_SIZE - 1u)
#define P1 2654435761u
#define P2 805459861u

// spatial binning: 5 bits/axis -> 32^3 bins, ~64 pts/bin at 2M pts.
#define NBB   5
#define NB1   (1 << NBB)
#define NBINS (1 << (3 * NBB))

struct ResArr { int r[L_LEVELS]; };
typedef float f32x4 __attribute__((ext_vector_type(4)));

// ---------------------------------------------------------------------------
// Per-point encode for one level.
// Slot model (calibrated R2-R8): L2 serves ~15 req-slots/cy/XCD; request
// count = distinct lines touched per instruction (cross-lane same-line
// merge -> sorting pays at levels whose wave-box < ~5 cells/axis, i.e.
// levels 0-7). ix even: one aligned float4 serves both x-paired corners.
// ---------------------------------------------------------------------------
__device__ __forceinline__ float2 encode_point(
    float px, float py, float pz, float rf,
    const float2* __restrict__ E, const float4* __restrict__ E4)
{
    // single fp32 multiplies to bit-match reference rounding
    const float sx = px * rf, sy = py * rf, sz = pz * rf;
    const int ix = (int)sx, iy = (int)sy, iz = (int)sz;  // x>=0 -> trunc==floor
    const float fx = sx - (float)ix;
    const float fy = sy - (float)iy;
    const float fz = sz - (float)iz;

    // hash keeps only low 19 bits -> uint32 arithmetic exact vs int64 reference
    const unsigned hx0 = (unsigned)ix,      hx1 = hx0 + 1u;
    const unsigned hy0 = (unsigned)iy * P1, hy1 = hy0 + P1;
    const unsigned hz0 = (unsigned)iz * P2, hz1 = hz0 + P2;
    const unsigned diffx = hx0 ^ hx1;      // 2^k-1 pattern, < 2^19 (ix<=2048)

    const unsigned h0 = (hx0 ^ hy0 ^ hz0) & T_MASK;
    const unsigned h1 = (hx0 ^ hy0 ^ hz1) & T_MASK;
    const unsigned h2 = (hx0 ^ hy1 ^ hz0) & T_MASK;
    const unsigned h3 = (hx0 ^ hy1 ^ hz1) & T_MASK;

    float2 c0v, c1v, c2v, c3v, c4v, c5v, c6v, c7v;

    if (diffx == 1u) {
        const float4 v0 = E4[h0 >> 1];
        const float4 v1 = E4[h1 >> 1];
        const float4 v2 = E4[h2 >> 1];
        const float4 v3 = E4[h3 >> 1];
        const bool o0 = (h0 & 1u), o1 = (h1 & 1u), o2 = (h2 & 1u), o3 = (h3 & 1u);
        c0v = o0 ? make_float2(v0.z, v0.w) : make_float2(v0.x, v0.y);
        c1v = o1 ? make_float2(v1.z, v1.w) : make_float2(v1.x, v1.y);
        c2v = o2 ? make_float2(v2.z, v2.w) : make_float2(v2.x, v2.y);
        c3v = o3 ? make_float2(v3.z, v3.w) : make_float2(v3.x, v3.y);
        c4v = o0 ? make_float2(v0.x, v0.y) : make_float2(v0.z, v0.w);
        c5v = o1 ? make_float2(v1.x, v1.y) : make_float2(v1.z, v1.w);
        c6v = o2 ? make_float2(v2.x, v2.y) : make_float2(v2.z, v2.w);
        c7v = o3 ? make_float2(v3.x, v3.y) : make_float2(v3.z, v3.w);
    } else {
        c0v = E[h0];
        c1v = E[h1];
        c2v = E[h2];
        c3v = E[h3];
        c4v = E[h0 ^ diffx];
        c5v = E[h1 ^ diffx];
        c6v = E[h2 ^ diffx];
        c7v = E[h3 ^ diffx];
    }

    const float gx = 1.0f - fx, gy = 1.0f - fy, gz = 1.0f - fz;
    // exact reference association: a*(1-f) + b*f
    const float c00x = c0v.x * gx + c4v.x * fx;
    const float c00y = c0v.y * gx + c4v.y * fx;
    const float c01x = c1v.x * gx + c5v.x * fx;
    const float c01y = c1v.y * gx + c5v.y * fx;
    const float c10x = c2v.x * gx + c6v.x * fx;
    const float c10y = c2v.y * gx + c6v.y * fx;
    const float c11x = c3v.x * gx + c7v.x * fx;
    const float c11y = c3v.y * gx + c7v.y * fx;

    const float a0x = c00x * gy + c10x * fy;
    const float a0y = c00y * gy + c10y * fy;
    const float a1x = c01x * gy + c11x * fy;
    const float a1y = c01y * gy + c11y * fy;

    return make_float2(a0x * gz + a1x * fz, a0y * gz + a1y * fz);
}

__device__ __forceinline__ unsigned bin_key(float px, float py, float pz)
{
    int bx = (int)(px * (float)NB1); bx = bx > NB1 - 1 ? NB1 - 1 : bx;
    int by = (int)(py * (float)NB1); by = by > NB1 - 1 ? NB1 - 1 : by;
    int bz = (int)(pz * (float)NB1); bz = bz > NB1 - 1 ? NB1 - 1 : bz;
    return (((unsigned)bz << NBB | (unsigned)by) << NBB) | (unsigned)bx;
}

// --------------------------- sort pipeline --------------------------------
__global__ __launch_bounds__(256) void hist_kernel(
    const float* __restrict__ x, unsigned* __restrict__ hist, int npts)
{
    int i = blockIdx.x * 256 + threadIdx.x;
    const int stride = gridDim.x * 256;
    for (; i < npts; i += stride) {
        const size_t b = (size_t)i * 3;
        atomicAdd(&hist[bin_key(x[b], x[b + 1], x[b + 2])], 1u);
    }
}

__global__ __launch_bounds__(1024) void scan_kernel(unsigned* __restrict__ hist)
{
    __shared__ unsigned wsum[16];
    const int t = threadIdx.x;
    const int CH = NBINS / 1024;         // 32
    unsigned v[NBINS / 1024];
    unsigned s = 0;
    #pragma unroll
    for (int j = 0; j < CH; ++j) { v[j] = hist[t * CH + j]; s += v[j]; }

    unsigned inc = s;
    #pragma unroll
    for (int d = 1; d < 64; d <<= 1) {
        const unsigned n = __shfl_up(inc, d, 64);
        if ((t & 63) >= d) inc += n;
    }
    const int wave = t >> 6;
    if ((t & 63) == 63) wsum[wave] = inc;
    __syncthreads();
    if (wave == 0) {
        const unsigned w = (t < 16) ? wsum[t] : 0u;
        unsigned winc = w;
        #pragma unroll
        for (int d = 1; d < 16; d <<= 1) {
            const unsigned n = __shfl_up(winc, d, 64);
            if (t >= d) winc += n;
        }
        if (t < 16) wsum[t] = winc - w;
    }
    __syncthreads();

    unsigned run = wsum[wave] + (inc - s);
    #pragma unroll
    for (int j = 0; j < CH; ++j) { const unsigned tmp = v[j]; hist[t * CH + j] = run; run += tmp; }
}

__global__ __launch_bounds__(256) void scatter_kernel(
    const float* __restrict__ x, unsigned* __restrict__ cursor,
    float4* __restrict__ xs4, int npts)
{
    __shared__ float xsh[768];
    const int tid = threadIdx.x, pbase = blockIdx.x * 256;
    if (pbase + 256 <= npts) {
        if (tid < 192)
            ((float4*)xsh)[tid] = ((const float4*)(x + (size_t)pbase * 3))[tid];
    } else {
        const int nfl = npts * 3 - pbase * 3;
        for (int i = tid; i < nfl; i += 256) xsh[i] = x[(size_t)pbase * 3 + i];
    }
    __syncthreads();
    const int p = pbase + tid;
    if (p >= npts) return;
    const float px = xsh[tid * 3], py = xsh[tid * 3 + 1], pz = xsh[tid * 3 + 2];
    const unsigned dest = atomicAdd(&cursor[bin_key(px, py, pz)], 1u);
    xs4[dest] = make_float4(px, py, pz, __uint_as_float((unsigned)p));
}

// ---------------------------------------------------------------------------
// K1 (sorted, HIGH levels only): grid (npts/256, 16-LSPLIT), y = level-LSPLIT.
// x-fastest dispatch => level-sequential => each XCD L2 holds the current
// 4MB table. High levels are hash-random (no cross-lane merge) — they carry
// ~58/72 of the old slot budget, so enc keeps only them; the mergeable
// levels 0..LSPLIT-1 moved into the store-bound unperm kernel (round 9).
// NT full-line ws stores (round-1 lesson: no partial-line scatter).
// ---------------------------------------------------------------------------
__global__ __launch_bounds__(256) void enc_level_sorted(
    const float4* __restrict__ xs4,
    const float* __restrict__ emb,
    float2* __restrict__ ws,
    ResArr res, int npts)
{
    const int level = LSPLIT + blockIdx.y;
    const int p = blockIdx.x * 256 + threadIdx.x;
    if (p >= npts) return;
    const float4 q = xs4[p];
    const float rf = (float)res.r[level];
    const float2* __restrict__ E  = (const float2*)emb + (size_t)level * T_SIZE;
    const float4* __restrict__ E4 = (const float4*)E;
    const float2 r = encode_point(q.x, q.y, q.z, rf, E, E4);
    union { float2 f2; double d; } u; u.f2 = r;
    __builtin_nontemporal_store(u.d,
        (double*)&ws[(size_t)(level - LSPLIT) * npts + p]);
}

// ---------------------------------------------------------------------------
// K2: recompute levels 0..LSPLIT-1 (sorted => tiny merged gather footprint,
// rides free under the scattered-store DRAM latency), NT-load levels
// LSPLIT..15 from ws, unpermute, store full 128B rows to out[orig].
// Store phase: 8 lanes/row => each wave-instr writes 8 contiguous 128B
// extents (full lines, no RFO).
// ---------------------------------------------------------------------------
__global__ __launch_bounds__(256) void transpose_unperm_kernel(
    const float2* __restrict__ ws, const float4* __restrict__ xs4,
    const float* __restrict__ emb,
    float4* __restrict__ out4, ResArr res, int npts)
{
    __shared__ float2 tile[256 * 17];
    __shared__ unsigned pidx[256];
    const int t = threadIdx.x, pbase = blockIdx.x * 256;
    const double* __restrict__ wsd = (const double*)ws;

    if (pbase + 256 <= npts) {
        const float4 q = xs4[pbase + t];
        pidx[t] = __float_as_uint(q.w);

        // high levels from ws: 512B/wave/instr contiguous NT loads
        #pragma unroll
        for (int l = LSPLIT; l < L_LEVELS; ++l) {
            const double tmp = __builtin_nontemporal_load(
                &wsd[(size_t)(l - LSPLIT) * npts + pbase + t]);
            *(double*)&tile[t * 17 + l] = tmp;
        }
        // low levels recomputed (slot-cheap in sorted order)
        #pragma unroll 1
        for (int l = 0; l < LSPLIT; ++l) {
            const float rf = (float)res.r[l];
            const float2* E  = (const float2*)emb + (size_t)l * T_SIZE;
            const float4* E4 = (const float4*)E;
            tile[t * 17 + l] = encode_point(q.x, q.y, q.z, rf, E, E4);
        }
        __syncthreads();

        #pragma unroll
        for (int pass = 0; pass < 8; ++pass) {
            const int r = pass * 32 + (t >> 3);  // local row (point)
            const int k = t & 7;                 // float4 within 128B row
            const size_t prow = (size_t)pidx[r];
            const float2 a = tile[r * 17 + 2 * k];
            const float2 b = tile[r * 17 + 2 * k + 1];
            f32x4 v; v.x = a.x; v.y = a.y; v.z = b.x; v.w = b.y;
            __builtin_nontemporal_store(v, (f32x4*)&out4[prow * 8 + k]);
        }
    } else {
        const int p = pbase + t;
        float4 q = make_float4(0.f, 0.f, 0.f, 0.f);
        if (p < npts) {
            q = xs4[p];
            pidx[t] = __float_as_uint(q.w);
            for (int l = LSPLIT; l < L_LEVELS; ++l)
                tile[t * 17 + l] = ws[(size_t)(l - LSPLIT) * npts + p];
            #pragma unroll 1
            for (int l = 0; l < LSPLIT; ++l) {
                const float rf = (float)res.r[l];
                const float2* E  = (const float2*)emb + (size_t)l * T_SIZE;
                const float4* E4 = (const float4*)E;
                tile[t * 17 + l] = encode_point(q.x, q.y, q.z, rf, E, E4);
            }
        }
        __syncthreads();
        if (p < npts) {
            const size_t prow = (size_t)pidx[t];
            for (int k = 0; k < 8; ++k) {
                const float2 a = tile[t * 17 + 2 * k];
                const float2 b = tile[t * 17 + 2 * k + 1];
                out4[prow * 8 + k] = make_float4(a.x, a.y, b.x, b.y);
            }
        }
    }
}

// ---------------------------------------------------------------------------
// R6 path (fallback if ws can't fit sort buffers): unsorted 16-level enc + K2.
// ---------------------------------------------------------------------------
__global__ __launch_bounds__(256) void enc_level_kernel(
    const float* __restrict__ x,
    const float* __restrict__ emb,
    float2* __restrict__ ws,
    ResArr res, int npts)
{
    __shared__ float xsh[768];
    const int tid   = threadIdx.x;
    const int level = blockIdx.y;
    const int pbase = blockIdx.x * 256;

    if (pbase + 256 <= npts) {
        if (tid < 192)
            ((float4*)xsh)[tid] = ((const float4*)(x + (size_t)pbase * 3))[tid];
    } else {
        const int nfl = npts * 3 - pbase * 3;
        for (int i = tid; i < nfl; i += 256) xsh[i] = x[(size_t)pbase * 3 + i];
    }
    __syncthreads();

    const int p = pbase + tid;
    if (p >= npts) return;

    const float rf = (float)res.r[level];
    const float2* __restrict__ E  = (const float2*)emb + (size_t)level * T_SIZE;
    const float4* __restrict__ E4 = (const float4*)E;

    const float2 r = encode_point(xsh[tid * 3 + 0], xsh[tid * 3 + 1],
                                  xsh[tid * 3 + 2], rf, E, E4);
    ws[(size_t)level * npts + p] = r;
}

__global__ __launch_bounds__(256) void transpose_tile_kernel(
    const float2* __restrict__ ws, float4* __restrict__ out4, int npts)
{
    __shared__ float2 tile[256 * 17];
    const int t     = threadIdx.x;
    const int pbase = blockIdx.x * 256;

    if (pbase + 256 <= npts) {
        #pragma unroll
        for (int l = 0; l < L_LEVELS; ++l)
            tile[t * 17 + l] = ws[(size_t)l * npts + pbase + t];
        __syncthreads();
        #pragma unroll
        for (int i = 0; i < 8; ++i) {
            const int jl = i * 256 + t;
            const int pl = jl >> 3;
            const int k  = jl & 7;
            const float2 a = tile[pl * 17 + 2 * k];
            const float2 b = tile[pl * 17 + 2 * k + 1];
            out4[(size_t)pbase * 8 + jl] = make_float4(a.x, a.y, b.x, b.y);
        }
    } else {
        const int p = pbase + t;
        if (p < npts) {
            #pragma unroll
            for (int l = 0; l < L_LEVELS; ++l)
                tile[t * 17 + l] = ws[(size_t)l * npts + p];
        }
        __syncthreads();
        const int npts_loc = npts - pbase;
        for (int i = 0; i < 8; ++i) {
            const int jl = i * 256 + t;
            const int pl = jl >> 3;
            const int k  = jl & 7;
            if (pl < npts_loc) {
                const float2 a = tile[pl * 17 + 2 * k];
                const float2 b = tile[pl * 17 + 2 * k + 1];
                out4[(size_t)pbase * 8 + jl] = make_float4(a.x, a.y, b.x, b.y);
            }
        }
    }
}

__global__ __launch_bounds__(256) void hash_enc_fallback(
    const float* __restrict__ x,
    const float* __restrict__ emb,
    float* __restrict__ out,
    ResArr res, int npts)
{
    __shared__ float xsh[48];
    const int tid = threadIdx.x;
    const int blockPointBase = blockIdx.x * 16;
    if (tid < 48) xsh[tid] = x[(size_t)blockPointBase * 3 + tid];
    __syncthreads();

    const int lp    = tid >> 4;
    const int level = tid & 15;
    const int p     = blockPointBase + lp;
    if (p >= npts) return;

    const float rf = (float)res.r[level];
    const float2* __restrict__ E  = (const float2*)emb + (size_t)level * T_SIZE;
    const float4* __restrict__ E4 = (const float4*)E;

    const float2 r = encode_point(xsh[lp * 3 + 0], xsh[lp * 3 + 1],
                                  xsh[lp * 3 + 2], rf, E, E4);
    ((float2*)out)[(size_t)p * 16 + level] = r;
}

extern "C" void kernel_launch(void* const* d_in, const int* in_sizes, int n_in,
                              void* d_out, int out_size, void* d_ws, size_t ws_size,
                              hipStream_t stream) {
    const float* x   = (const float*)d_in[0];
    const float* emb = (const float*)d_in[1];

    // Replicate Python: b = exp((log(2048)-log(16))/15); res_i = floor(16*b**i)
    ResArr res;
    const double b = exp((log(2048.0) - log(16.0)) / 15.0);
    for (int i = 0; i < L_LEVELS; ++i)
        res.r[i] = (int)floor(16.0 * pow(b, (double)i));

    const int npts = in_sizes[0] / 3;
    const int pblocks = (npts + 255) / 256;

    const size_t ws2_bytes  = (size_t)npts * (L_LEVELS - LSPLIT) * sizeof(float2);
    const size_t xs4_bytes  = (size_t)npts * sizeof(float4);
    const size_t hist_bytes = (size_t)NBINS * sizeof(unsigned);
    const size_t need_sorted = ws2_bytes + xs4_bytes + hist_bytes;
    const size_t ws_full    = (size_t)npts * L_LEVELS * sizeof(float2);

    if (ws_size >= need_sorted) {
        float2*   ws2  = (float2*)d_ws;
        float4*   xs4  = (float4*)((char*)d_ws + ws2_bytes);
        unsigned* hist = (unsigned*)((char*)d_ws + ws2_bytes + xs4_bytes);

        hipMemsetAsync(hist, 0, hist_bytes, stream);
        hipLaunchKernelGGL(hist_kernel, dim3(2048), dim3(256), 0, stream,
                           x, hist, npts);
        hipLaunchKernelGGL(scan_kernel, dim3(1), dim3(1024), 0, stream, hist);
        hipLaunchKernelGGL(scatter_kernel, dim3(pblocks), dim3(256), 0, stream,
                           x, hist, xs4, npts);
        hipLaunchKernelGGL(enc_level_sorted,
                           dim3(pblocks, L_LEVELS - LSPLIT), dim3(256),
                           0, stream, xs4, emb, ws2, res, npts);
        hipLaunchKernelGGL(transpose_unperm_kernel, dim3(pblocks), dim3(256),
                           0, stream, ws2, xs4, emb, (float4*)d_out, res, npts);
    } else if (ws_size >= ws_full) {
        float2* ws = (float2*)d_ws;
        hipLaunchKernelGGL(enc_level_kernel, dim3(pblocks, L_LEVELS), dim3(256),
                           0, stream, x, emb, ws, res, npts);
        hipLaunchKernelGGL(transpose_tile_kernel, dim3(pblocks), dim3(256),
                           0, stream, ws, (float4*)d_out, npts);
    } else {
        const int blocks = (npts + 15) / 16;
        hipLaunchKernelGGL(hash_enc_fallback, dim3(blocks), dim3(256),
                           0, stream, x, emb, (float*)d_out, res, npts);
    }
}